// Round 9
// baseline (759.130 us; speedup 1.0000x reference)
//
#include <hip/hip_runtime.h>
#include <hip/hip_cooperative_groups.h>

namespace cg = cooperative_groups;

#define IN_DIM 128
#define OUT_DIM 128
#define BM 64      // nodes per block (f32 fallback GEMM)
#define KT 32      // k-tile (f32 fallback GEMM)

typedef __attribute__((ext_vector_type(8))) short short8v;   // 8 bf16 (4 VGPR)
typedef __attribute__((ext_vector_type(4))) float float4v;   // 4 fp32
typedef __attribute__((ext_vector_type(4))) float f4v;

// ---- bf16 split helpers ----------------------------------------------------
__device__ __forceinline__ unsigned short bf16_hi(float x) {
    unsigned int u = __float_as_uint(x);
    return (unsigned short)((u + 0x7fffu + ((u >> 16) & 1u)) >> 16);
}
__device__ __forceinline__ float bf16_tof(unsigned short h) {
    return __uint_as_float(((unsigned int)h) << 16);
}

// ===========================================================================
// fused_all (cooperative): phase A {zero counts | wsplit | xsplit} -> hist ->
// scan x3 -> bucket -> accum_split. Grid-stride everywhere; host checks rc.
// ===========================================================================
__global__ __launch_bounds__(256, 4)
void fused_all_kernel(const float* __restrict__ X,
                      const int* __restrict__ src,
                      const int* __restrict__ dst,
                      const float* __restrict__ Wself,
                      const float* __restrict__ Wneigh,
                      int* __restrict__ counts,
                      int* __restrict__ offs,
                      int* __restrict__ cursor,
                      int* __restrict__ bsums,
                      int* __restrict__ srcsorted,
                      unsigned short* __restrict__ Ahi,
                      unsigned short* __restrict__ Alo,
                      unsigned short* __restrict__ W1h,
                      unsigned short* __restrict__ W1l,
                      unsigned short* __restrict__ W2h,
                      unsigned short* __restrict__ W2l,
                      unsigned short* __restrict__ Xsp,   // = d_out
                      int n_nodes, int n_edges, int nb) {
    cg::grid_group grid = cg::this_grid();
    __shared__ int tmp[256];
    __shared__ int carry;

    const int tid   = threadIdx.x;
    const int gsize = gridDim.x * 256;
    const int gtid  = blockIdx.x * 256 + tid;

    // ---- phase A: independent inits ----
    for (int i = gtid; i < n_nodes; i += gsize) counts[i] = 0;
    for (int i = gtid; i < OUT_DIM * IN_DIM; i += gsize) {
        float a = Wself[i], b = Wneigh[i];
        unsigned short ah = bf16_hi(a), bh = bf16_hi(b);
        W1h[i] = ah; W1l[i] = bf16_hi(a - bf16_tof(ah));
        W2h[i] = bh; W2l[i] = bf16_hi(b - bf16_tof(bh));
    }
    for (int i = gtid; i < n_nodes * 32; i += gsize) {   // xsplit
        const int node = i >> 5, g = i & 31;
        const float4 x = *reinterpret_cast<const float4*>(
            X + (size_t)node * IN_DIM + g * 4);
        ushort4 hi, lo;
        hi.x = bf16_hi(x.x); lo.x = bf16_hi(x.x - bf16_tof(hi.x));
        hi.y = bf16_hi(x.y); lo.y = bf16_hi(x.y - bf16_tof(hi.y));
        hi.z = bf16_hi(x.z); lo.z = bf16_hi(x.z - bf16_tof(hi.z));
        hi.w = bf16_hi(x.w); lo.w = bf16_hi(x.w - bf16_tof(hi.w));
        *reinterpret_cast<ushort4*>(Xsp + (size_t)node * 256 + g * 4) = hi;
        *reinterpret_cast<ushort4*>(Xsp + (size_t)node * 256 + 128 + g * 4) = lo;
    }
    grid.sync();

    // ---- phase B: histogram of dst ----
    {
        const int n4 = n_edges >> 2;
        for (int i = gtid; i < n4; i += gsize) {
            int4 d4 = reinterpret_cast<const int4*>(dst)[i];
            atomicAdd(&counts[d4.x], 1);
            atomicAdd(&counts[d4.y], 1);
            atomicAdd(&counts[d4.z], 1);
            atomicAdd(&counts[d4.w], 1);
        }
        for (int e = (n4 << 2) + gtid; e < n_edges; e += gsize)
            atomicAdd(&counts[dst[e]], 1);
    }
    grid.sync();

    // ---- phase C: per-256-chunk exclusive scan ----
    for (int ci = blockIdx.x; ci < nb; ci += gridDim.x) {
        const int i = ci * 256 + tid;
        const int v = (i < n_nodes) ? counts[i] : 0;
        tmp[tid] = v;
        __syncthreads();
        #pragma unroll
        for (int d = 1; d < 256; d <<= 1) {
            int t = (tid >= d) ? tmp[tid - d] : 0;
            __syncthreads();
            tmp[tid] += t;
            __syncthreads();
        }
        if (i < n_nodes) offs[i] = tmp[tid] - v;
        if (tid == 255) bsums[ci] = tmp[255];
        __syncthreads();
    }
    grid.sync();

    // ---- phase D: scan block sums (block 0) ----
    if (blockIdx.x == 0) {
        if (tid == 0) carry = 0;
        __syncthreads();
        for (int base = 0; base < nb; base += 256) {
            const int i = base + tid;
            const int v = (i < nb) ? bsums[i] : 0;
            tmp[tid] = v;
            __syncthreads();
            #pragma unroll
            for (int d = 1; d < 256; d <<= 1) {
                int t = (tid >= d) ? tmp[tid - d] : 0;
                __syncthreads();
                tmp[tid] += t;
                __syncthreads();
            }
            if (i < nb) bsums[i] = carry + tmp[tid] - v;
            __syncthreads();
            if (tid == 0) carry += tmp[255];
            __syncthreads();
        }
    }
    grid.sync();

    // ---- phase E: finalize offs, init cursor ----
    for (int i = gtid; i < n_nodes; i += gsize) {
        const int o = offs[i] + bsums[i >> 8];
        offs[i] = o;
        cursor[i] = o;
    }
    grid.sync();

    // ---- phase F: bucket edges ----
    for (int e = gtid; e < n_edges; e += gsize) {
        const int pos = atomicAdd(&cursor[dst[e]], 1);
        srcsorted[pos] = src[e];
    }
    grid.sync();

    // ---- phase G: accum + bf16 hi/lo split (8-wide unroll) ----
    {
        const int sub  = tid & 31;
        const int grp  = gtid >> 5;
        const int ngrp = gsize >> 5;
        for (int u = grp; u < n_nodes; u += ngrp) {
            const int beg = offs[u];
            const int end = (u == n_nodes - 1) ? n_edges : offs[u + 1];
            f4v a0 = (f4v)0.f, a1 = (f4v)0.f;
            int e = beg;
            for (; e + 8 <= end; e += 8) {
                const int s0 = srcsorted[e + 0];
                const int s1 = srcsorted[e + 1];
                const int s2 = srcsorted[e + 2];
                const int s3 = srcsorted[e + 3];
                const int s4 = srcsorted[e + 4];
                const int s5 = srcsorted[e + 5];
                const int s6 = srcsorted[e + 6];
                const int s7 = srcsorted[e + 7];
                f4v v0 = *reinterpret_cast<const f4v*>(X + (size_t)s0 * IN_DIM + sub * 4);
                f4v v1 = *reinterpret_cast<const f4v*>(X + (size_t)s1 * IN_DIM + sub * 4);
                f4v v2 = *reinterpret_cast<const f4v*>(X + (size_t)s2 * IN_DIM + sub * 4);
                f4v v3 = *reinterpret_cast<const f4v*>(X + (size_t)s3 * IN_DIM + sub * 4);
                f4v v4 = *reinterpret_cast<const f4v*>(X + (size_t)s4 * IN_DIM + sub * 4);
                f4v v5 = *reinterpret_cast<const f4v*>(X + (size_t)s5 * IN_DIM + sub * 4);
                f4v v6 = *reinterpret_cast<const f4v*>(X + (size_t)s6 * IN_DIM + sub * 4);
                f4v v7 = *reinterpret_cast<const f4v*>(X + (size_t)s7 * IN_DIM + sub * 4);
                a0 += v0 + v1 + v2 + v3;
                a1 += v4 + v5 + v6 + v7;
            }
            for (; e + 4 <= end; e += 4) {
                const int s0 = srcsorted[e + 0];
                const int s1 = srcsorted[e + 1];
                const int s2 = srcsorted[e + 2];
                const int s3 = srcsorted[e + 3];
                f4v v0 = *reinterpret_cast<const f4v*>(X + (size_t)s0 * IN_DIM + sub * 4);
                f4v v1 = *reinterpret_cast<const f4v*>(X + (size_t)s1 * IN_DIM + sub * 4);
                f4v v2 = *reinterpret_cast<const f4v*>(X + (size_t)s2 * IN_DIM + sub * 4);
                f4v v3 = *reinterpret_cast<const f4v*>(X + (size_t)s3 * IN_DIM + sub * 4);
                a0 += v0 + v1;
                a1 += v2 + v3;
            }
            for (; e < end; ++e) {
                const int s = srcsorted[e];
                a0 += *reinterpret_cast<const f4v*>(X + (size_t)s * IN_DIM + sub * 4);
            }
            const f4v r = a0 + a1;
            ushort4 hi, lo;
            hi.x = bf16_hi(r.x); lo.x = bf16_hi(r.x - bf16_tof(hi.x));
            hi.y = bf16_hi(r.y); lo.y = bf16_hi(r.y - bf16_tof(hi.y));
            hi.z = bf16_hi(r.z); lo.z = bf16_hi(r.z - bf16_tof(hi.z));
            hi.w = bf16_hi(r.w); lo.w = bf16_hi(r.w - bf16_tof(hi.w));
            *reinterpret_cast<ushort4*>(Ahi + (size_t)u * IN_DIM + sub * 4) = hi;
            *reinterpret_cast<ushort4*>(Alo + (size_t)u * IN_DIM + sub * 4) = lo;
        }
    }
}

// ===========================================================================
// Discrete chain (primary when coop is rejected under capture).
// prep = memset(counts) + wsplit + xsplit fused (independent elementwise).
// ===========================================================================
__global__ __launch_bounds__(256)
void prep_kernel(const float* __restrict__ X,
                 const float* __restrict__ Wself,
                 const float* __restrict__ Wneigh,
                 int* __restrict__ counts,
                 unsigned short* __restrict__ W1h,
                 unsigned short* __restrict__ W1l,
                 unsigned short* __restrict__ W2h,
                 unsigned short* __restrict__ W2l,
                 unsigned short* __restrict__ Xsp,
                 int n_nodes) {
    const int gtid  = blockIdx.x * 256 + threadIdx.x;
    const int gsize = gridDim.x * 256;

    for (int i = gtid; i < n_nodes; i += gsize) counts[i] = 0;

    for (int i = gtid; i < OUT_DIM * IN_DIM; i += gsize) {
        float a = Wself[i], b = Wneigh[i];
        unsigned short ah = bf16_hi(a), bh = bf16_hi(b);
        W1h[i] = ah; W1l[i] = bf16_hi(a - bf16_tof(ah));
        W2h[i] = bh; W2l[i] = bf16_hi(b - bf16_tof(bh));
    }

    for (int i = gtid; i < n_nodes * 32; i += gsize) {
        const int node = i >> 5, g = i & 31;
        const float4 x = *reinterpret_cast<const float4*>(
            X + (size_t)node * IN_DIM + g * 4);
        ushort4 hi, lo;
        hi.x = bf16_hi(x.x); lo.x = bf16_hi(x.x - bf16_tof(hi.x));
        hi.y = bf16_hi(x.y); lo.y = bf16_hi(x.y - bf16_tof(hi.y));
        hi.z = bf16_hi(x.z); lo.z = bf16_hi(x.z - bf16_tof(hi.z));
        hi.w = bf16_hi(x.w); lo.w = bf16_hi(x.w - bf16_tof(hi.w));
        *reinterpret_cast<ushort4*>(Xsp + (size_t)node * 256 + g * 4) = hi;
        *reinterpret_cast<ushort4*>(Xsp + (size_t)node * 256 + 128 + g * 4) = lo;
    }
}

__global__ void hist_kernel(const int* __restrict__ dst, int* __restrict__ counts,
                            int n_edges) {
    int i = blockIdx.x * blockDim.x + threadIdx.x;
    int e0 = i * 4;
    if (e0 + 4 <= n_edges) {
        int4 d4 = *reinterpret_cast<const int4*>(dst + e0);
        atomicAdd(&counts[d4.x], 1);
        atomicAdd(&counts[d4.y], 1);
        atomicAdd(&counts[d4.z], 1);
        atomicAdd(&counts[d4.w], 1);
    } else {
        for (int e = e0; e < n_edges; ++e) atomicAdd(&counts[dst[e]], 1);
    }
}

__global__ __launch_bounds__(256)
void scan1_kernel(const int* __restrict__ counts, int* __restrict__ offs,
                  int* __restrict__ bsums, int n) {
    __shared__ int tmp[256];
    const int tid = threadIdx.x;
    const int i = blockIdx.x * 256 + tid;
    const int v = (i < n) ? counts[i] : 0;
    tmp[tid] = v;
    __syncthreads();
    #pragma unroll
    for (int d = 1; d < 256; d <<= 1) {
        int t = (tid >= d) ? tmp[tid - d] : 0;
        __syncthreads();
        tmp[tid] += t;
        __syncthreads();
    }
    if (i < n) offs[i] = tmp[tid] - v;
    if (tid == 255) bsums[blockIdx.x] = tmp[255];
}

__global__ __launch_bounds__(256)
void scan2_kernel(int* __restrict__ bsums, int nb) {
    __shared__ int tmp[256];
    __shared__ int carry;
    const int tid = threadIdx.x;
    if (tid == 0) carry = 0;
    __syncthreads();
    for (int base = 0; base < nb; base += 256) {
        const int i = base + tid;
        const int v = (i < nb) ? bsums[i] : 0;
        tmp[tid] = v;
        __syncthreads();
        #pragma unroll
        for (int d = 1; d < 256; d <<= 1) {
            int t = (tid >= d) ? tmp[tid - d] : 0;
            __syncthreads();
            tmp[tid] += t;
            __syncthreads();
        }
        if (i < nb) bsums[i] = carry + tmp[tid] - v;
        __syncthreads();
        if (tid == 0) carry += tmp[255];
        __syncthreads();
    }
}

__global__ __launch_bounds__(256)
void scan3_kernel(int* __restrict__ offs, const int* __restrict__ bsums,
                  int* __restrict__ cursor, int n) {
    const int i = blockIdx.x * 256 + threadIdx.x;
    if (i < n) {
        const int o = offs[i] + bsums[blockIdx.x];
        offs[i] = o;
        cursor[i] = o;
    }
}

__global__ void bucket_kernel(const int* __restrict__ src,
                              const int* __restrict__ dst,
                              int* __restrict__ cursor,
                              int* __restrict__ src_sorted, int n_edges) {
    int e = blockIdx.x * blockDim.x + threadIdx.x;
    if (e < n_edges) {
        const int pos = atomicAdd(&cursor[dst[e]], 1);
        src_sorted[pos] = src[e];
    }
}

// accum with 8-edge unroll (discrete, grid-stride)
__global__ __launch_bounds__(256)
void accum8_kernel(const float* __restrict__ X,
                   const int* __restrict__ offs,
                   const int* __restrict__ src_sorted,
                   unsigned short* __restrict__ Ahi,
                   unsigned short* __restrict__ Alo,
                   int n_nodes, int n_edges) {
    const int tid   = threadIdx.x;
    const int sub   = tid & 31;
    const int grp   = (blockIdx.x * 256 + tid) >> 5;
    const int ngrp  = (gridDim.x * 256) >> 5;
    for (int u = grp; u < n_nodes; u += ngrp) {
        const int beg = offs[u];
        const int end = (u == n_nodes - 1) ? n_edges : offs[u + 1];
        f4v a0 = (f4v)0.f, a1 = (f4v)0.f;
        int e = beg;
        for (; e + 8 <= end; e += 8) {
            const int s0 = src_sorted[e + 0];
            const int s1 = src_sorted[e + 1];
            const int s2 = src_sorted[e + 2];
            const int s3 = src_sorted[e + 3];
            const int s4 = src_sorted[e + 4];
            const int s5 = src_sorted[e + 5];
            const int s6 = src_sorted[e + 6];
            const int s7 = src_sorted[e + 7];
            f4v v0 = *reinterpret_cast<const f4v*>(X + (size_t)s0 * IN_DIM + sub * 4);
            f4v v1 = *reinterpret_cast<const f4v*>(X + (size_t)s1 * IN_DIM + sub * 4);
            f4v v2 = *reinterpret_cast<const f4v*>(X + (size_t)s2 * IN_DIM + sub * 4);
            f4v v3 = *reinterpret_cast<const f4v*>(X + (size_t)s3 * IN_DIM + sub * 4);
            f4v v4 = *reinterpret_cast<const f4v*>(X + (size_t)s4 * IN_DIM + sub * 4);
            f4v v5 = *reinterpret_cast<const f4v*>(X + (size_t)s5 * IN_DIM + sub * 4);
            f4v v6 = *reinterpret_cast<const f4v*>(X + (size_t)s6 * IN_DIM + sub * 4);
            f4v v7 = *reinterpret_cast<const f4v*>(X + (size_t)s7 * IN_DIM + sub * 4);
            a0 += v0 + v1 + v2 + v3;
            a1 += v4 + v5 + v6 + v7;
        }
        for (; e + 4 <= end; e += 4) {
            const int s0 = src_sorted[e + 0];
            const int s1 = src_sorted[e + 1];
            const int s2 = src_sorted[e + 2];
            const int s3 = src_sorted[e + 3];
            f4v v0 = *reinterpret_cast<const f4v*>(X + (size_t)s0 * IN_DIM + sub * 4);
            f4v v1 = *reinterpret_cast<const f4v*>(X + (size_t)s1 * IN_DIM + sub * 4);
            f4v v2 = *reinterpret_cast<const f4v*>(X + (size_t)s2 * IN_DIM + sub * 4);
            f4v v3 = *reinterpret_cast<const f4v*>(X + (size_t)s3 * IN_DIM + sub * 4);
            a0 += v0 + v1;
            a1 += v2 + v3;
        }
        for (; e < end; ++e) {
            const int s = src_sorted[e];
            a0 += *reinterpret_cast<const f4v*>(X + (size_t)s * IN_DIM + sub * 4);
        }
        const f4v r = a0 + a1;
        ushort4 hi, lo;
        hi.x = bf16_hi(r.x); lo.x = bf16_hi(r.x - bf16_tof(hi.x));
        hi.y = bf16_hi(r.y); lo.y = bf16_hi(r.y - bf16_tof(hi.y));
        hi.z = bf16_hi(r.z); lo.z = bf16_hi(r.z - bf16_tof(hi.z));
        hi.w = bf16_hi(r.w); lo.w = bf16_hi(r.w - bf16_tof(hi.w));
        *reinterpret_cast<ushort4*>(Ahi + (size_t)u * IN_DIM + sub * 4) = hi;
        *reinterpret_cast<ushort4*>(Alo + (size_t)u * IN_DIM + sub * 4) = lo;
    }
}

// ===========================================================================
// MFMA GEMM — VERBATIM the R3-proven kernel (passed, absmax 0.03125).
// out[n][o] = relu( sum of 6 bf16 K-segments + bias ), K=6*128.
// ===========================================================================
__global__ __launch_bounds__(256, 4)
void mfma_gemm_kernel(const unsigned short* Xsp,          // aliases `out`!
                      const unsigned short* __restrict__ Ahi,
                      const unsigned short* __restrict__ Alo,
                      const unsigned short* __restrict__ W1h,
                      const unsigned short* __restrict__ W1l,
                      const unsigned short* __restrict__ W2h,
                      const unsigned short* __restrict__ W2l,
                      const float* __restrict__ bias,
                      float* out,
                      int n_nodes) {
    __shared__ unsigned short Fs[64 * 64];    // [node][k] swizzled, 8 KB
    __shared__ unsigned short Ws[128 * 64];   // [o][k]    swizzled, 16 KB

    const int tid  = threadIdx.x;
    const int lane = tid & 63;
    const int wid  = tid >> 6;
    const int wm   = wid >> 1;
    const int wn   = wid & 1;
    const int lr   = lane & 15;
    const int lk   = lane >> 4;
    const int node0 = blockIdx.x * 64;

    const int fr = tid >> 3;
    const int c  = tid & 7;
    const int swz = (c ^ (fr & 7)) * 8;

    float4v acc[2][4];
    #pragma unroll
    for (int mi = 0; mi < 2; ++mi)
        #pragma unroll
        for (int ni = 0; ni < 4; ++ni) acc[mi][ni] = (float4v)0.f;

    const unsigned short* wseg[6] = {W1h, W1l, W1h, W2h, W2l, W2h};

    short8v fv[2], wv[4];

    {
        const int khalf = 0;
        #pragma unroll
        for (int j = 0; j < 2; ++j) {
            const int node = node0 + fr + j * 32;
            short8v v = (short8v)0;
            if (node < n_nodes)
                v = *reinterpret_cast<const short8v*>(
                    Xsp + (size_t)node * 256 + khalf + c * 8);
            fv[j] = v;
        }
        #pragma unroll
        for (int j = 0; j < 4; ++j)
            wv[j] = *reinterpret_cast<const short8v*>(
                wseg[0] + (size_t)(fr + j * 32) * 128 + khalf + c * 8);
    }

    #pragma unroll
    for (int t = 0; t < 12; ++t) {
        __syncthreads();
        #pragma unroll
        for (int j = 0; j < 2; ++j)
            *reinterpret_cast<short8v*>(&Fs[(fr + j * 32) * 64 + swz]) = fv[j];
        #pragma unroll
        for (int j = 0; j < 4; ++j)
            *reinterpret_cast<short8v*>(&Ws[(fr + j * 32) * 64 + swz]) = wv[j];
        __syncthreads();

        if (t < 11) {
            const int tn = t + 1;
            const int seg = tn >> 1;
            const int khalf = (tn & 1) * 64;
            #pragma unroll
            for (int j = 0; j < 2; ++j) {
                const int node = node0 + fr + j * 32;
                short8v v = (short8v)0;
                if (node < n_nodes) {
                    if (seg < 3) {
                        v = *reinterpret_cast<const short8v*>(
                            Xsp + (size_t)node * 256 + (seg == 2 ? 128 : 0) +
                            khalf + c * 8);
                    } else {
                        const unsigned short* Ap = (seg == 5) ? Alo : Ahi;
                        v = *reinterpret_cast<const short8v*>(
                            Ap + (size_t)node * 128 + khalf + c * 8);
                    }
                }
                fv[j] = v;
            }
            #pragma unroll
            for (int j = 0; j < 4; ++j)
                wv[j] = *reinterpret_cast<const short8v*>(
                    wseg[seg] + (size_t)(fr + j * 32) * 128 + khalf + c * 8);
        }

        #pragma unroll
        for (int ks = 0; ks < 2; ++ks) {
            const int cc = ((ks * 4 + lk) ^ (lr & 7)) * 8;
            short8v a[2], b[4];
            #pragma unroll
            for (int mi = 0; mi < 2; ++mi) {
                const int row = wm * 32 + mi * 16 + lr;
                a[mi] = *reinterpret_cast<const short8v*>(&Fs[row * 64 + cc]);
            }
            #pragma unroll
            for (int ni = 0; ni < 4; ++ni) {
                const int o = wn * 64 + ni * 16 + lr;
                b[ni] = *reinterpret_cast<const short8v*>(&Ws[o * 64 + cc]);
            }
            #pragma unroll
            for (int mi = 0; mi < 2; ++mi)
                #pragma unroll
                for (int ni = 0; ni < 4; ++ni)
                    acc[mi][ni] = __builtin_amdgcn_mfma_f32_16x16x32_bf16(
                        a[mi], b[ni], acc[mi][ni], 0, 0, 0);
        }
    }

    #pragma unroll
    for (int ni = 0; ni < 4; ++ni) {
        const int o = wn * 64 + ni * 16 + lr;
        const float bo = bias[o];
        #pragma unroll
        for (int mi = 0; mi < 2; ++mi) {
            const int nodeb = node0 + wm * 32 + mi * 16 + lk * 4;
            #pragma unroll
            for (int r = 0; r < 4; ++r) {
                const int node = nodeb + r;
                if (node < n_nodes)
                    out[(size_t)node * OUT_DIM + o] =
                        fmaxf(acc[mi][ni][r] + bo, 0.f);
            }
        }
    }
}

// ===========================================================================
// ws-too-small fallback: f32 atomics + f32 GEMM (R1/R2-proven)
// ===========================================================================
__global__ void scatter_kernel(const float* __restrict__ X,
                               const int* __restrict__ src,
                               const int* __restrict__ dst,
                               float* __restrict__ A,
                               int n_edges) {
    int gtid = blockIdx.x * blockDim.x + threadIdx.x;
    int e = gtid >> 5;
    if (e >= n_edges) return;
    int sub = gtid & 31;
    int s = src[e];
    int d = dst[e];
    const float4 v = *reinterpret_cast<const float4*>(
        X + (size_t)s * IN_DIM + sub * 4);
    float* o = A + (size_t)d * IN_DIM + sub * 4;
    unsafeAtomicAdd(o + 0, v.x);
    unsafeAtomicAdd(o + 1, v.y);
    unsafeAtomicAdd(o + 2, v.z);
    unsafeAtomicAdd(o + 3, v.w);
}

__global__ __launch_bounds__(256)
void gemm_kernel(const float* __restrict__ X,
                 const float* __restrict__ A,
                 const float* __restrict__ Wself,
                 const float* __restrict__ Wneigh,
                 const float* __restrict__ bias,
                 float* __restrict__ out,
                 int n_nodes) {
    __shared__ alignas(16) float Wt[KT][132];
    __shared__ alignas(16) float Xs[BM][KT + 4];
    const int tid   = threadIdx.x;
    const int o_grp = tid & 31;
    const int n_grp = tid >> 5;
    const int node0 = blockIdx.x * BM;
    float acc[8][4];
    #pragma unroll
    for (int i = 0; i < 8; ++i)
        #pragma unroll
        for (int j = 0; j < 4; ++j) acc[i][j] = 0.f;
    for (int kt = 0; kt < 2 * IN_DIM; kt += KT) {
        const float* Wsrc = (kt < IN_DIM) ? Wself : Wneigh;
        const float* Fsrc = (kt < IN_DIM) ? X : A;
        const int kbase = kt & (IN_DIM - 1);
        __syncthreads();
        {
            const int k4 = tid & 7;
            int o = tid >> 3;
            #pragma unroll
            for (int p = 0; p < 4; ++p, o += 32) {
                float4 w = *reinterpret_cast<const float4*>(
                    Wsrc + o * IN_DIM + kbase + k4 * 4);
                Wt[k4 * 4 + 0][o] = w.x;
                Wt[k4 * 4 + 1][o] = w.y;
                Wt[k4 * 4 + 2][o] = w.z;
                Wt[k4 * 4 + 3][o] = w.w;
            }
        }
        {
            const int k4 = tid & 7;
            int n = tid >> 3;
            #pragma unroll
            for (int p = 0; p < 2; ++p, n += 32) {
                const int node = node0 + n;
                float4 x = make_float4(0.f, 0.f, 0.f, 0.f);
                if (node < n_nodes)
                    x = *reinterpret_cast<const float4*>(
                        Fsrc + (size_t)node * IN_DIM + kbase + k4 * 4);
                *reinterpret_cast<float4*>(&Xs[n][k4 * 4]) = x;
            }
        }
        __syncthreads();
        #pragma unroll
        for (int k4 = 0; k4 < KT; k4 += 4) {
            float4 w0 = *reinterpret_cast<const float4*>(&Wt[k4 + 0][o_grp * 4]);
            float4 w1 = *reinterpret_cast<const float4*>(&Wt[k4 + 1][o_grp * 4]);
            float4 w2 = *reinterpret_cast<const float4*>(&Wt[k4 + 2][o_grp * 4]);
            float4 w3 = *reinterpret_cast<const float4*>(&Wt[k4 + 3][o_grp * 4]);
            #pragma unroll
            for (int nn = 0; nn < 8; ++nn) {
                float4 x = *reinterpret_cast<const float4*>(
                    &Xs[n_grp * 8 + nn][k4]);
                acc[nn][0] = fmaf(x.x, w0.x, acc[nn][0]);
                acc[nn][0] = fmaf(x.y, w1.x, acc[nn][0]);
                acc[nn][0] = fmaf(x.z, w2.x, acc[nn][0]);
                acc[nn][0] = fmaf(x.w, w3.x, acc[nn][0]);
                acc[nn][1] = fmaf(x.x, w0.y, acc[nn][1]);
                acc[nn][1] = fmaf(x.y, w1.y, acc[nn][1]);
                acc[nn][1] = fmaf(x.z, w2.y, acc[nn][1]);
                acc[nn][1] = fmaf(x.w, w3.y, acc[nn][1]);
                acc[nn][2] = fmaf(x.x, w0.z, acc[nn][2]);
                acc[nn][2] = fmaf(x.y, w1.z, acc[nn][2]);
                acc[nn][2] = fmaf(x.z, w2.z, acc[nn][2]);
                acc[nn][2] = fmaf(x.w, w3.z, acc[nn][2]);
                acc[nn][3] = fmaf(x.x, w0.w, acc[nn][3]);
                acc[nn][3] = fmaf(x.y, w1.w, acc[nn][3]);
                acc[nn][3] = fmaf(x.z, w2.w, acc[nn][3]);
                acc[nn][3] = fmaf(x.w, w3.w, acc[nn][3]);
            }
        }
    }
    const float4 b = *reinterpret_cast<const float4*>(bias + o_grp * 4);
    #pragma unroll
    for (int nn = 0; nn < 8; ++nn) {
        const int node = node0 + n_grp * 8 + nn;
        if (node < n_nodes) {
            float4 r;
            r.x = fmaxf(acc[nn][0] + b.x, 0.f);
            r.y = fmaxf(acc[nn][1] + b.y, 0.f);
            r.z = fmaxf(acc[nn][2] + b.z, 0.f);
            r.w = fmaxf(acc[nn][3] + b.w, 0.f);
            *reinterpret_cast<float4*>(
                out + (size_t)node * OUT_DIM + o_grp * 4) = r;
        }
    }
}

// ===========================================================================
extern "C" void kernel_launch(void* const* d_in, const int* in_sizes, int n_in,
                              void* d_out, int out_size, void* d_ws, size_t ws_size,
                              hipStream_t stream) {
    const float* X      = (const float*)d_in[0];
    const int*   src    = (const int*)d_in[1];
    const int*   dst    = (const int*)d_in[2];
    const float* Wself  = (const float*)d_in[3];
    const float* Wneigh = (const float*)d_in[4];
    const float* bias   = (const float*)d_in[5];
    float*       out    = (float*)d_out;

    int n_nodes = in_sizes[0] / IN_DIM;
    int n_edges = in_sizes[1];
    int nb = (n_nodes + 255) / 256;

    char* w = (char*)d_ws;
    auto take = [&](size_t bytes) {
        char* p = w;
        w += (bytes + 15) & ~(size_t)15;
        return p;
    };
    unsigned short* Ahi = (unsigned short*)take((size_t)n_nodes * IN_DIM * 2);
    unsigned short* Alo = (unsigned short*)take((size_t)n_nodes * IN_DIM * 2);
    int* counts    = (int*)take((size_t)n_nodes * sizeof(int));
    int* offs      = (int*)take((size_t)n_nodes * sizeof(int));
    int* cursor    = (int*)take((size_t)n_nodes * sizeof(int));
    int* bsums     = (int*)take((size_t)nb * sizeof(int));
    int* srcsorted = (int*)take((size_t)n_edges * sizeof(int));
    unsigned short* W1h = (unsigned short*)take((size_t)OUT_DIM * IN_DIM * 2);
    unsigned short* W1l = (unsigned short*)take((size_t)OUT_DIM * IN_DIM * 2);
    unsigned short* W2h = (unsigned short*)take((size_t)OUT_DIM * IN_DIM * 2);
    unsigned short* W2l = (unsigned short*)take((size_t)OUT_DIM * IN_DIM * 2);
    const size_t needed = (size_t)(w - (char*)d_ws);

    if (needed <= ws_size) {
        unsigned short* Xsp = (unsigned short*)d_out;   // X hi/lo packed in out

        // ---- try the fused cooperative kernel; rc-checked fallback ----
        bool coop_ok = false;
        int maxb = 0;
        hipError_t oerr = hipOccupancyMaxActiveBlocksPerMultiprocessor(
            &maxb, (const void*)fused_all_kernel, 256, 0);
        if (oerr == hipSuccess && maxb > 0) {
            int grid = maxb * 256;           // 256 CUs on MI355X
            if (grid > 1024) grid = 1024;
            void* args[] = {(void*)&X, (void*)&src, (void*)&dst,
                            (void*)&Wself, (void*)&Wneigh,
                            (void*)&counts, (void*)&offs, (void*)&cursor,
                            (void*)&bsums, (void*)&srcsorted,
                            (void*)&Ahi, (void*)&Alo,
                            (void*)&W1h, (void*)&W1l, (void*)&W2h, (void*)&W2l,
                            (void*)&Xsp,
                            (void*)&n_nodes, (void*)&n_edges, (void*)&nb};
            hipError_t cerr = hipLaunchCooperativeKernel(
                (void*)fused_all_kernel, dim3(grid), dim3(256), args, 0, stream);
            coop_ok = (cerr == hipSuccess);
        }

        if (!coop_ok) {
            // ---- discrete chain (prep-fused, accum 8-wide) ----
            const int eblocks = (n_edges + 255) / 256;
            prep_kernel<<<2048, 256, 0, stream>>>(
                X, Wself, Wneigh, counts, W1h, W1l, W2h, W2l, Xsp, n_nodes);
            hist_kernel<<<(n_edges / 4 + 256) / 256 + 1, 256, 0, stream>>>(
                dst, counts, n_edges);
            scan1_kernel<<<nb, 256, 0, stream>>>(counts, offs, bsums, n_nodes);
            scan2_kernel<<<1, 256, 0, stream>>>(bsums, nb);
            scan3_kernel<<<nb, 256, 0, stream>>>(offs, bsums, cursor, n_nodes);
            bucket_kernel<<<eblocks, 256, 0, stream>>>(src, dst, cursor,
                                                       srcsorted, n_edges);
            accum8_kernel<<<2048, 256, 0, stream>>>(
                X, offs, srcsorted, Ahi, Alo, n_nodes, n_edges);
        }

        mfma_gemm_kernel<<<(n_nodes + 63) / 64, 256, 0, stream>>>(
            Xsp, Ahi, Alo, W1h, W1l, W2h, W2l, bias, out, n_nodes);
    } else {
        // ---- ws-too-small fallback ----
        float* Af = (float*)d_ws;
        hipMemsetAsync(Af, 0, (size_t)n_nodes * IN_DIM * sizeof(float), stream);
        const long long sthreads = (long long)n_edges * 32;
        const int sblocks = (int)((sthreads + 255) / 256);
        scatter_kernel<<<sblocks, 256, 0, stream>>>(X, src, dst, Af, n_edges);
        gemm_kernel<<<(n_nodes + BM - 1) / BM, 256, 0, stream>>>(
            X, Af, Wself, Wneigh, bias, out, n_nodes);
    }
}

// Round 11
// 272.417 us; speedup vs baseline: 2.7866x; 2.7866x over previous
//
#include <hip/hip_runtime.h>

#define IN_DIM 128
#define OUT_DIM 128
#define BM 64      // nodes per block (f32 fallback GEMM)
#define KT 32      // k-tile (f32 fallback GEMM)

typedef __attribute__((ext_vector_type(8))) short short8v;   // 8 bf16 (4 VGPR)
typedef __attribute__((ext_vector_type(4))) float float4v;   // 4 fp32 acc

// ---- bf16 split helpers ----------------------------------------------------
__device__ __forceinline__ unsigned short bf16_hi(float x) {
    unsigned int u = __float_as_uint(x);
    return (unsigned short)((u + 0x7fffu + ((u >> 16) & 1u)) >> 16);
}
__device__ __forceinline__ float bf16_tof(unsigned short h) {
    return __uint_as_float(((unsigned int)h) << 16);
}

// ===========================================================================
// Fallback path (R1): f32 atomics — only used if ws_size is too small.
// ===========================================================================
__global__ void scatter_kernel(const float* __restrict__ X,
                               const int* __restrict__ src,
                               const int* __restrict__ dst,
                               float* __restrict__ A,
                               int n_edges) {
    int gtid = blockIdx.x * blockDim.x + threadIdx.x;
    int e = gtid >> 5;
    if (e >= n_edges) return;
    int sub = gtid & 31;
    int s = src[e];
    int d = dst[e];
    const float4 v = *reinterpret_cast<const float4*>(
        X + (size_t)s * IN_DIM + sub * 4);
    float* o = A + (size_t)d * IN_DIM + sub * 4;
    unsafeAtomicAdd(o + 0, v.x);
    unsafeAtomicAdd(o + 1, v.y);
    unsafeAtomicAdd(o + 2, v.z);
    unsafeAtomicAdd(o + 3, v.w);
}

// ===========================================================================
// CSR binning
// ===========================================================================
__global__ void hist_kernel(const int* __restrict__ dst, int* __restrict__ counts,
                            int n_edges) {
    int i = blockIdx.x * blockDim.x + threadIdx.x;   // 1 thread = 4 edges
    int e0 = i * 4;
    if (e0 + 4 <= n_edges) {
        int4 d4 = *reinterpret_cast<const int4*>(dst + e0);
        atomicAdd(&counts[d4.x], 1);
        atomicAdd(&counts[d4.y], 1);
        atomicAdd(&counts[d4.z], 1);
        atomicAdd(&counts[d4.w], 1);
    } else {
        for (int e = e0; e < n_edges; ++e) atomicAdd(&counts[dst[e]], 1);
    }
}

__global__ __launch_bounds__(256)
void scan1_kernel(const int* __restrict__ counts, int* __restrict__ offs,
                  int* __restrict__ bsums, int n) {
    __shared__ int tmp[256];
    const int tid = threadIdx.x;
    const int i = blockIdx.x * 256 + tid;
    const int v = (i < n) ? counts[i] : 0;
    tmp[tid] = v;
    __syncthreads();
    #pragma unroll
    for (int d = 1; d < 256; d <<= 1) {
        int t = (tid >= d) ? tmp[tid - d] : 0;
        __syncthreads();
        tmp[tid] += t;
        __syncthreads();
    }
    if (i < n) offs[i] = tmp[tid] - v;
    if (tid == 255) bsums[blockIdx.x] = tmp[255];
}

__global__ __launch_bounds__(256)
void scan2_kernel(int* __restrict__ bsums, int nb) {
    __shared__ int tmp[256];
    __shared__ int carry;
    const int tid = threadIdx.x;
    if (tid == 0) carry = 0;
    __syncthreads();
    for (int base = 0; base < nb; base += 256) {
        const int i = base + tid;
        const int v = (i < nb) ? bsums[i] : 0;
        tmp[tid] = v;
        __syncthreads();
        #pragma unroll
        for (int d = 1; d < 256; d <<= 1) {
            int t = (tid >= d) ? tmp[tid - d] : 0;
            __syncthreads();
            tmp[tid] += t;
            __syncthreads();
        }
        if (i < nb) bsums[i] = carry + tmp[tid] - v;
        __syncthreads();
        if (tid == 0) carry += tmp[255];
        __syncthreads();
    }
}

__global__ __launch_bounds__(256)
void scan3_kernel(int* __restrict__ offs, const int* __restrict__ bsums,
                  int* __restrict__ cursor, int n) {
    const int i = blockIdx.x * 256 + threadIdx.x;
    if (i < n) {
        const int o = offs[i] + bsums[blockIdx.x];
        offs[i] = o;
        cursor[i] = o;
    }
}

__global__ void bucket_kernel(const int* __restrict__ src,
                              const int* __restrict__ dst,
                              int* __restrict__ cursor,
                              int* __restrict__ src_sorted, int n_edges) {
    int e = blockIdx.x * blockDim.x + threadIdx.x;
    if (e < n_edges) {
        const int pos = atomicAdd(&cursor[dst[e]], 1);
        src_sorted[pos] = src[e];
    }
}

// A[u] = sum X[src] over incoming edges; emits bf16 hi/lo split.
// 32 lanes per node, float4/lane, 4-edge unroll for MLP.
__global__ __launch_bounds__(256)
void accum_split_kernel(const float* __restrict__ X,
                        const int* __restrict__ offs,
                        const int* __restrict__ src_sorted,
                        unsigned short* __restrict__ Ahi,
                        unsigned short* __restrict__ Alo,
                        int n_nodes, int n_edges) {
    const int tid = threadIdx.x;
    const int u = blockIdx.x * 8 + (tid >> 5);
    if (u >= n_nodes) return;
    const int sub = tid & 31;

    const int beg = offs[u];
    const int end = (u == n_nodes - 1) ? n_edges : offs[u + 1];

    float4 acc = make_float4(0.f, 0.f, 0.f, 0.f);
    int e = beg;
    for (; e + 4 <= end; e += 4) {
        const int s0 = src_sorted[e + 0];
        const int s1 = src_sorted[e + 1];
        const int s2 = src_sorted[e + 2];
        const int s3 = src_sorted[e + 3];
        const float4 v0 = *reinterpret_cast<const float4*>(X + (size_t)s0 * IN_DIM + sub * 4);
        const float4 v1 = *reinterpret_cast<const float4*>(X + (size_t)s1 * IN_DIM + sub * 4);
        const float4 v2 = *reinterpret_cast<const float4*>(X + (size_t)s2 * IN_DIM + sub * 4);
        const float4 v3 = *reinterpret_cast<const float4*>(X + (size_t)s3 * IN_DIM + sub * 4);
        acc.x += v0.x + v1.x + v2.x + v3.x;
        acc.y += v0.y + v1.y + v2.y + v3.y;
        acc.z += v0.z + v1.z + v2.z + v3.z;
        acc.w += v0.w + v1.w + v2.w + v3.w;
    }
    for (; e < end; ++e) {
        const int s = src_sorted[e];
        const float4 v = *reinterpret_cast<const float4*>(X + (size_t)s * IN_DIM + sub * 4);
        acc.x += v.x; acc.y += v.y; acc.z += v.z; acc.w += v.w;
    }

    ushort4 hi, lo;
    hi.x = bf16_hi(acc.x); lo.x = bf16_hi(acc.x - bf16_tof(hi.x));
    hi.y = bf16_hi(acc.y); lo.y = bf16_hi(acc.y - bf16_tof(hi.y));
    hi.z = bf16_hi(acc.z); lo.z = bf16_hi(acc.z - bf16_tof(hi.z));
    hi.w = bf16_hi(acc.w); lo.w = bf16_hi(acc.w - bf16_tof(hi.w));
    *reinterpret_cast<ushort4*>(Ahi + (size_t)u * IN_DIM + sub * 4) = hi;
    *reinterpret_cast<ushort4*>(Alo + (size_t)u * IN_DIM + sub * 4) = lo;
}

// ===========================================================================
// xsplit: X f32 -> per-node packed [hi[128] | lo[128]] bf16, stored in d_out.
// ===========================================================================
__global__ void xsplit_kernel(const float* __restrict__ X,
                              unsigned short* __restrict__ Xsp, int n_nodes) {
    int i = blockIdx.x * blockDim.x + threadIdx.x;   // n_nodes*32 float4 groups
    if (i >= n_nodes * 32) return;
    const int node = i >> 5, g = i & 31;
    const float4 x = *reinterpret_cast<const float4*>(X + (size_t)node * IN_DIM + g * 4);
    ushort4 hi, lo;
    hi.x = bf16_hi(x.x); lo.x = bf16_hi(x.x - bf16_tof(hi.x));
    hi.y = bf16_hi(x.y); lo.y = bf16_hi(x.y - bf16_tof(hi.y));
    hi.z = bf16_hi(x.z); lo.z = bf16_hi(x.z - bf16_tof(hi.z));
    hi.w = bf16_hi(x.w); lo.w = bf16_hi(x.w - bf16_tof(hi.w));
    *reinterpret_cast<ushort4*>(Xsp + (size_t)node * 256 + g * 4) = hi;
    *reinterpret_cast<ushort4*>(Xsp + (size_t)node * 256 + 128 + g * 4) = lo;
}

__global__ void wsplit_kernel(const float* __restrict__ W1,
                              const float* __restrict__ W2,
                              unsigned short* __restrict__ W1h,
                              unsigned short* __restrict__ W1l,
                              unsigned short* __restrict__ W2h,
                              unsigned short* __restrict__ W2l) {
    int i = blockIdx.x * blockDim.x + threadIdx.x;   // 16384
    if (i >= OUT_DIM * IN_DIM) return;
    float a = W1[i], b = W2[i];
    unsigned short ah = bf16_hi(a), bh = bf16_hi(b);
    W1h[i] = ah; W1l[i] = bf16_hi(a - bf16_tof(ah));
    W2h[i] = bh; W2l[i] = bf16_hi(b - bf16_tof(bh));
}

// ===========================================================================
// MFMA GEMM: out[n][o] = relu( sum over 6 bf16 K-segments + bias )
// segs: Xhi*W1h, Xhi*W1l, Xlo*W1h, Ahi*W2h, Ahi*W2l, Alo*W2h  (K=6*128=768)
// ===========================================================================
__global__ __launch_bounds__(256, 4)
void mfma_gemm_kernel(const unsigned short* Xsp,          // aliases `out`!
                      const unsigned short* __restrict__ Ahi,
                      const unsigned short* __restrict__ Alo,
                      const unsigned short* __restrict__ W1h,
                      const unsigned short* __restrict__ W1l,
                      const unsigned short* __restrict__ W2h,
                      const unsigned short* __restrict__ W2l,
                      const float* __restrict__ bias,
                      float* out,
                      int n_nodes) {
    __shared__ unsigned short Fs[64 * 64];    // [node][k] swizzled, 8 KB
    __shared__ unsigned short Ws[128 * 64];   // [o][k]    swizzled, 16 KB

    const int tid  = threadIdx.x;
    const int lane = tid & 63;
    const int wid  = tid >> 6;
    const int wm   = wid >> 1;          // 0..1  (node half)
    const int wn   = wid & 1;           // 0..1  (out half)
    const int lr   = lane & 15;
    const int lk   = lane >> 4;         // 0..3
    const int node0 = blockIdx.x * 64;

    const int fr = tid >> 3;            // base row 0..31
    const int c  = tid & 7;             // chunk in row
    const int swz = (c ^ (fr & 7)) * 8; // LDS-side swizzled element offset

    float4v acc[2][4];
    #pragma unroll
    for (int mi = 0; mi < 2; ++mi)
        #pragma unroll
        for (int ni = 0; ni < 4; ++ni) acc[mi][ni] = (float4v)0.f;

    const unsigned short* wseg[6] = {W1h, W1l, W1h, W2h, W2l, W2h};

    short8v fv[2], wv[4];

    // ---- prologue: load tile 0 ----
    {
        const int khalf = 0;
        #pragma unroll
        for (int j = 0; j < 2; ++j) {
            const int node = node0 + fr + j * 32;
            short8v v = (short8v)0;
            if (node < n_nodes)
                v = *reinterpret_cast<const short8v*>(
                    Xsp + (size_t)node * 256 + khalf + c * 8);
            fv[j] = v;
        }
        #pragma unroll
        for (int j = 0; j < 4; ++j)
            wv[j] = *reinterpret_cast<const short8v*>(
                wseg[0] + (size_t)(fr + j * 32) * 128 + khalf + c * 8);
    }

    #pragma unroll
    for (int t = 0; t < 12; ++t) {
        __syncthreads();   // protect LDS from previous tile's readers
        #pragma unroll
        for (int j = 0; j < 2; ++j)
            *reinterpret_cast<short8v*>(&Fs[(fr + j * 32) * 64 + swz]) = fv[j];
        #pragma unroll
        for (int j = 0; j < 4; ++j)
            *reinterpret_cast<short8v*>(&Ws[(fr + j * 32) * 64 + swz]) = wv[j];
        __syncthreads();

        // ---- prefetch tile t+1 (hides under MFMA phase) ----
        if (t < 11) {
            const int tn = t + 1;
            const int seg = tn >> 1;
            const int khalf = (tn & 1) * 64;
            #pragma unroll
            for (int j = 0; j < 2; ++j) {
                const int node = node0 + fr + j * 32;
                short8v v = (short8v)0;
                if (node < n_nodes) {
                    if (seg < 3) {
                        v = *reinterpret_cast<const short8v*>(
                            Xsp + (size_t)node * 256 + (seg == 2 ? 128 : 0) +
                            khalf + c * 8);
                    } else {
                        const unsigned short* Ap = (seg == 5) ? Alo : Ahi;
                        v = *reinterpret_cast<const short8v*>(
                            Ap + (size_t)node * 128 + khalf + c * 8);
                    }
                }
                fv[j] = v;
            }
            #pragma unroll
            for (int j = 0; j < 4; ++j)
                wv[j] = *reinterpret_cast<const short8v*>(
                    wseg[seg] + (size_t)(fr + j * 32) * 128 + khalf + c * 8);
        }

        // ---- compute tile t ----
        #pragma unroll
        for (int ks = 0; ks < 2; ++ks) {
            const int cc = ((ks * 4 + lk) ^ (lr & 7)) * 8;
            short8v a[2], b[4];
            #pragma unroll
            for (int mi = 0; mi < 2; ++mi) {
                const int row = wm * 32 + mi * 16 + lr;
                a[mi] = *reinterpret_cast<const short8v*>(&Fs[row * 64 + cc]);
            }
            #pragma unroll
            for (int ni = 0; ni < 4; ++ni) {
                const int o = wn * 64 + ni * 16 + lr;
                b[ni] = *reinterpret_cast<const short8v*>(&Ws[o * 64 + cc]);
            }
            #pragma unroll
            for (int mi = 0; mi < 2; ++mi)
                #pragma unroll
                for (int ni = 0; ni < 4; ++ni)
                    acc[mi][ni] = __builtin_amdgcn_mfma_f32_16x16x32_bf16(
                        a[mi], b[ni], acc[mi][ni], 0, 0, 0);
        }
    }

    // ---- epilogue: bias + relu; C/D layout col=lane&15, row=(lane>>4)*4+r ----
    #pragma unroll
    for (int ni = 0; ni < 4; ++ni) {
        const int o = wn * 64 + ni * 16 + lr;
        const float bo = bias[o];
        #pragma unroll
        for (int mi = 0; mi < 2; ++mi) {
            const int nodeb = node0 + wm * 32 + mi * 16 + lk * 4;
            #pragma unroll
            for (int r = 0; r < 4; ++r) {
                const int node = nodeb + r;
                if (node < n_nodes)
                    out[(size_t)node * OUT_DIM + o] =
                        fmaxf(acc[mi][ni][r] + bo, 0.f);
            }
        }
    }
}

// ===========================================================================
// f32 fallback GEMM (R2-proven)
// ===========================================================================
__global__ __launch_bounds__(256)
void gemm_kernel(const float* __restrict__ X,
                 const float* __restrict__ A,
                 const float* __restrict__ Wself,
                 const float* __restrict__ Wneigh,
                 const float* __restrict__ bias,
                 float* __restrict__ out,
                 int n_nodes) {
    __shared__ alignas(16) float Wt[KT][132];
    __shared__ alignas(16) float Xs[BM][KT + 4];

    const int tid   = threadIdx.x;
    const int o_grp = tid & 31;
    const int n_grp = tid >> 5;
    const int node0 = blockIdx.x * BM;

    float acc[8][4];
    #pragma unroll
    for (int i = 0; i < 8; ++i)
        #pragma unroll
        for (int j = 0; j < 4; ++j) acc[i][j] = 0.f;

    for (int kt = 0; kt < 2 * IN_DIM; kt += KT) {
        const float* Wsrc = (kt < IN_DIM) ? Wself : Wneigh;
        const float* Fsrc = (kt < IN_DIM) ? X : A;
        const int kbase = kt & (IN_DIM - 1);
        __syncthreads();
        {
            const int k4 = tid & 7;
            int o = tid >> 3;
            #pragma unroll
            for (int p = 0; p < 4; ++p, o += 32) {
                float4 w = *reinterpret_cast<const float4*>(
                    Wsrc + o * IN_DIM + kbase + k4 * 4);
                Wt[k4 * 4 + 0][o] = w.x;
                Wt[k4 * 4 + 1][o] = w.y;
                Wt[k4 * 4 + 2][o] = w.z;
                Wt[k4 * 4 + 3][o] = w.w;
            }
        }
        {
            const int k4 = tid & 7;
            int n = tid >> 3;
            #pragma unroll
            for (int p = 0; p < 2; ++p, n += 32) {
                const int node = node0 + n;
                float4 x = make_float4(0.f, 0.f, 0.f, 0.f);
                if (node < n_nodes)
                    x = *reinterpret_cast<const float4*>(
                        Fsrc + (size_t)node * IN_DIM + kbase + k4 * 4);
                *reinterpret_cast<float4*>(&Xs[n][k4 * 4]) = x;
            }
        }
        __syncthreads();
        #pragma unroll
        for (int k4 = 0; k4 < KT; k4 += 4) {
            float4 w0 = *reinterpret_cast<const float4*>(&Wt[k4 + 0][o_grp * 4]);
            float4 w1 = *reinterpret_cast<const float4*>(&Wt[k4 + 1][o_grp * 4]);
            float4 w2 = *reinterpret_cast<const float4*>(&Wt[k4 + 2][o_grp * 4]);
            float4 w3 = *reinterpret_cast<const float4*>(&Wt[k4 + 3][o_grp * 4]);
            #pragma unroll
            for (int nn = 0; nn < 8; ++nn) {
                float4 x = *reinterpret_cast<const float4*>(
                    &Xs[n_grp * 8 + nn][k4]);
                acc[nn][0] = fmaf(x.x, w0.x, acc[nn][0]);
                acc[nn][0] = fmaf(x.y, w1.x, acc[nn][0]);
                acc[nn][0] = fmaf(x.z, w2.x, acc[nn][0]);
                acc[nn][0] = fmaf(x.w, w3.x, acc[nn][0]);
                acc[nn][1] = fmaf(x.x, w0.y, acc[nn][1]);
                acc[nn][1] = fmaf(x.y, w1.y, acc[nn][1]);
                acc[nn][1] = fmaf(x.z, w2.y, acc[nn][1]);
                acc[nn][1] = fmaf(x.w, w3.y, acc[nn][1]);
                acc[nn][2] = fmaf(x.x, w0.z, acc[nn][2]);
                acc[nn][2] = fmaf(x.y, w1.z, acc[nn][2]);
                acc[nn][2] = fmaf(x.z, w2.z, acc[nn][2]);
                acc[nn][2] = fmaf(x.w, w3.z, acc[nn][2]);
                acc[nn][3] = fmaf(x.x, w0.w, acc[nn][3]);
                acc[nn][3] = fmaf(x.y, w1.w, acc[nn][3]);
                acc[nn][3] = fmaf(x.z, w2.w, acc[nn][3]);
                acc[nn][3] = fmaf(x.w, w3.w, acc[nn][3]);
            }
        }
    }

    const float4 b = *reinterpret_cast<const float4*>(bias + o_grp * 4);
    #pragma unroll
    for (int nn = 0; nn < 8; ++nn) {
        const int node = node0 + n_grp * 8 + nn;
        if (node < n_nodes) {
            float4 r;
            r.x = fmaxf(acc[nn][0] + b.x, 0.f);
            r.y = fmaxf(acc[nn][1] + b.y, 0.f);
            r.z = fmaxf(acc[nn][2] + b.z, 0.f);
            r.w = fmaxf(acc[nn][3] + b.w, 0.f);
            *reinterpret_cast<float4*>(
                out + (size_t)node * OUT_DIM + o_grp * 4) = r;
        }
    }
}

// ===========================================================================
extern "C" void kernel_launch(void* const* d_in, const int* in_sizes, int n_in,
                              void* d_out, int out_size, void* d_ws, size_t ws_size,
                              hipStream_t stream) {
    const float* X      = (const float*)d_in[0];
    const int*   src    = (const int*)d_in[1];
    const int*   dst    = (const int*)d_in[2];
    const float* Wself  = (const float*)d_in[3];
    const float* Wneigh = (const float*)d_in[4];
    const float* bias   = (const float*)d_in[5];
    float*       out    = (float*)d_out;

    const int n_nodes = in_sizes[0] / IN_DIM;
    const int n_edges = in_sizes[1];
    const int nb = (n_nodes + 255) / 256;

    char* w = (char*)d_ws;
    auto take = [&](size_t bytes) {
        char* p = w;
        w += (bytes + 15) & ~(size_t)15;
        return p;
    };
    unsigned short* Ahi = (unsigned short*)take((size_t)n_nodes * IN_DIM * 2);
    unsigned short* Alo = (unsigned short*)take((size_t)n_nodes * IN_DIM * 2);
    int* counts    = (int*)take((size_t)n_nodes * sizeof(int));
    int* offs      = (int*)take((size_t)n_nodes * sizeof(int));
    int* cursor    = (int*)take((size_t)n_nodes * sizeof(int));
    int* bsums     = (int*)take((size_t)nb * sizeof(int));
    int* srcsorted = (int*)take((size_t)n_edges * sizeof(int));
    unsigned short* W1h = (unsigned short*)take((size_t)OUT_DIM * IN_DIM * 2);
    unsigned short* W1l = (unsigned short*)take((size_t)OUT_DIM * IN_DIM * 2);
    unsigned short* W2h = (unsigned short*)take((size_t)OUT_DIM * IN_DIM * 2);
    unsigned short* W2l = (unsigned short*)take((size_t)OUT_DIM * IN_DIM * 2);
    const size_t needed = (size_t)(w - (char*)d_ws);

    const int eblocks = (n_edges + 255) / 256;

    if (needed <= ws_size) {
        // ---- CSR binning + bf16x2-split MFMA path (R3-proven, verbatim) ----
        hipMemsetAsync(counts, 0, (size_t)n_nodes * sizeof(int), stream);
        hist_kernel<<<(n_edges / 4 + 256) / 256 + 1, 256, 0, stream>>>(dst, counts, n_edges);
        scan1_kernel<<<nb, 256, 0, stream>>>(counts, offs, bsums, n_nodes);
        scan2_kernel<<<1, 256, 0, stream>>>(bsums, nb);
        scan3_kernel<<<nb, 256, 0, stream>>>(offs, bsums, cursor, n_nodes);
        bucket_kernel<<<eblocks, 256, 0, stream>>>(src, dst, cursor, srcsorted,
                                                   n_edges);
        unsigned short* Xsp = (unsigned short*)d_out;   // X hi/lo packed in out slots
        xsplit_kernel<<<(n_nodes * 32 + 255) / 256, 256, 0, stream>>>(X, Xsp, n_nodes);
        wsplit_kernel<<<(OUT_DIM * IN_DIM + 255) / 256, 256, 0, stream>>>(
            Wself, Wneigh, W1h, W1l, W2h, W2l);
        accum_split_kernel<<<(n_nodes + 7) / 8, 256, 0, stream>>>(
            X, offs, srcsorted, Ahi, Alo, n_nodes, n_edges);
        mfma_gemm_kernel<<<(n_nodes + 63) / 64, 256, 0, stream>>>(
            Xsp, Ahi, Alo, W1h, W1l, W2h, W2l, bias, out, n_nodes);
    } else {
        // ---- fallback: f32 atomic scatter + f32 vector GEMM ----
        float* A = (float*)d_ws;
        hipMemsetAsync(A, 0, (size_t)n_nodes * IN_DIM * sizeof(float), stream);
        const long long sthreads = (long long)n_edges * 32;
        const int sblocks = (int)((sthreads + 255) / 256);
        scatter_kernel<<<sblocks, 256, 0, stream>>>(X, src, dst, A, n_edges);
        gemm_kernel<<<(n_nodes + BM - 1) / BM, 256, 0, stream>>>(
            X, A, Wself, Wneigh, bias, out, n_nodes);
    }
}

// Round 12
// 263.720 us; speedup vs baseline: 2.8785x; 1.0330x over previous
//
#include <hip/hip_runtime.h>

#define IN_DIM 128
#define OUT_DIM 128
#define BM 64      // nodes per block (f32 fallback GEMM)
#define KT 32      // k-tile (f32 fallback GEMM)
#define NPART 8    // dst-range partitions for bucket scatter (XCD count)

typedef __attribute__((ext_vector_type(8))) short short8v;   // 8 bf16 (4 VGPR)
typedef __attribute__((ext_vector_type(4))) float float4v;   // 4 fp32 acc

// ---- bf16 split helpers ----------------------------------------------------
__device__ __forceinline__ unsigned short bf16_hi(float x) {
    unsigned int u = __float_as_uint(x);
    return (unsigned short)((u + 0x7fffu + ((u >> 16) & 1u)) >> 16);
}
__device__ __forceinline__ float bf16_tof(unsigned short h) {
    return __uint_as_float(((unsigned int)h) << 16);
}

// ===========================================================================
// Fallback path (R1): f32 atomics — only used if ws_size is too small.
// ===========================================================================
__global__ void scatter_kernel(const float* __restrict__ X,
                               const int* __restrict__ src,
                               const int* __restrict__ dst,
                               float* __restrict__ A,
                               int n_edges) {
    int gtid = blockIdx.x * blockDim.x + threadIdx.x;
    int e = gtid >> 5;
    if (e >= n_edges) return;
    int sub = gtid & 31;
    int s = src[e];
    int d = dst[e];
    const float4 v = *reinterpret_cast<const float4*>(
        X + (size_t)s * IN_DIM + sub * 4);
    float* o = A + (size_t)d * IN_DIM + sub * 4;
    unsafeAtomicAdd(o + 0, v.x);
    unsafeAtomicAdd(o + 1, v.y);
    unsafeAtomicAdd(o + 2, v.z);
    unsafeAtomicAdd(o + 3, v.w);
}

// ===========================================================================
// CSR binning
// ===========================================================================
__global__ void hist_kernel(const int* __restrict__ dst, int* __restrict__ counts,
                            int n_edges) {
    int i = blockIdx.x * blockDim.x + threadIdx.x;   // 1 thread = 4 edges
    int e0 = i * 4;
    if (e0 + 4 <= n_edges) {
        int4 d4 = *reinterpret_cast<const int4*>(dst + e0);
        atomicAdd(&counts[d4.x], 1);
        atomicAdd(&counts[d4.y], 1);
        atomicAdd(&counts[d4.z], 1);
        atomicAdd(&counts[d4.w], 1);
    } else {
        for (int e = e0; e < n_edges; ++e) atomicAdd(&counts[dst[e]], 1);
    }
}

__global__ __launch_bounds__(256)
void scan1_kernel(const int* __restrict__ counts, int* __restrict__ offs,
                  int* __restrict__ bsums, int n) {
    __shared__ int tmp[256];
    const int tid = threadIdx.x;
    const int i = blockIdx.x * 256 + tid;
    const int v = (i < n) ? counts[i] : 0;
    tmp[tid] = v;
    __syncthreads();
    #pragma unroll
    for (int d = 1; d < 256; d <<= 1) {
        int t = (tid >= d) ? tmp[tid - d] : 0;
        __syncthreads();
        tmp[tid] += t;
        __syncthreads();
    }
    if (i < n) offs[i] = tmp[tid] - v;
    if (tid == 255) bsums[blockIdx.x] = tmp[255];
}

__global__ __launch_bounds__(256)
void scan2_kernel(int* __restrict__ bsums, int nb) {
    __shared__ int tmp[256];
    __shared__ int carry;
    const int tid = threadIdx.x;
    if (tid == 0) carry = 0;
    __syncthreads();
    for (int base = 0; base < nb; base += 256) {
        const int i = base + tid;
        const int v = (i < nb) ? bsums[i] : 0;
        tmp[tid] = v;
        __syncthreads();
        #pragma unroll
        for (int d = 1; d < 256; d <<= 1) {
            int t = (tid >= d) ? tmp[tid - d] : 0;
            __syncthreads();
            tmp[tid] += t;
            __syncthreads();
        }
        if (i < nb) bsums[i] = carry + tmp[tid] - v;
        __syncthreads();
        if (tid == 0) carry += tmp[255];
        __syncthreads();
    }
}

__global__ __launch_bounds__(256)
void scan3_kernel(int* __restrict__ offs, const int* __restrict__ bsums,
                  int* __restrict__ cursor, int n) {
    const int i = blockIdx.x * 256 + threadIdx.x;
    if (i < n) {
        const int o = offs[i] + bsums[blockIdx.x];
        offs[i] = o;
        cursor[i] = o;
    }
}

// ===========================================================================
// bucket, dst-range partitioned: part p = blockIdx&7 handles dst in
// [p*chunk,(p+1)*chunk). Aligned with the blockIdx%8 -> XCD round-robin, so
// each srcsorted region + its cursors are written by ONE XCD's L2 only
// (kills the 16x cross-XCD line ping-pong measured in R11: WRITE 52.6MB).
// Correct regardless of actual XCD mapping; edges read NPART x (LLC-cached).
// ===========================================================================
__global__ __launch_bounds__(256)
void bucket_part_kernel(const int* __restrict__ src,
                        const int* __restrict__ dst,
                        int* __restrict__ cursor,
                        int* __restrict__ src_sorted,
                        int n_edges, int chunk) {
    const int part = blockIdx.x & (NPART - 1);
    const int lb   = blockIdx.x / NPART;           // block within part group
    const int gt   = lb * 256 + threadIdx.x;       // thread within part group
    const int gstr = (gridDim.x / NPART) * 256;    // part-group stride
    const int lo = part * chunk;
    const int hi = lo + chunk;

    const int n4 = n_edges >> 2;
    for (int i = gt; i < n4; i += gstr) {
        const int4 d4 = reinterpret_cast<const int4*>(dst)[i];
        const int4 s4 = reinterpret_cast<const int4*>(src)[i];
        if (d4.x >= lo && d4.x < hi)
            src_sorted[atomicAdd(&cursor[d4.x], 1)] = s4.x;
        if (d4.y >= lo && d4.y < hi)
            src_sorted[atomicAdd(&cursor[d4.y], 1)] = s4.y;
        if (d4.z >= lo && d4.z < hi)
            src_sorted[atomicAdd(&cursor[d4.z], 1)] = s4.z;
        if (d4.w >= lo && d4.w < hi)
            src_sorted[atomicAdd(&cursor[d4.w], 1)] = s4.w;
    }
    for (int e = (n4 << 2) + gt; e < n_edges; e += gstr) {
        const int d = dst[e];
        if (d >= lo && d < hi)
            src_sorted[atomicAdd(&cursor[d], 1)] = src[e];
    }
}

// A[u] = sum X[src] over incoming edges; emits bf16 hi/lo split.
__global__ __launch_bounds__(256)
void accum_split_kernel(const float* __restrict__ X,
                        const int* __restrict__ offs,
                        const int* __restrict__ src_sorted,
                        unsigned short* __restrict__ Ahi,
                        unsigned short* __restrict__ Alo,
                        int n_nodes, int n_edges) {
    const int tid = threadIdx.x;
    const int u = blockIdx.x * 8 + (tid >> 5);
    if (u >= n_nodes) return;
    const int sub = tid & 31;

    const int beg = offs[u];
    const int end = (u == n_nodes - 1) ? n_edges : offs[u + 1];

    float4 acc = make_float4(0.f, 0.f, 0.f, 0.f);
    int e = beg;
    for (; e + 4 <= end; e += 4) {
        const int s0 = src_sorted[e + 0];
        const int s1 = src_sorted[e + 1];
        const int s2 = src_sorted[e + 2];
        const int s3 = src_sorted[e + 3];
        const float4 v0 = *reinterpret_cast<const float4*>(X + (size_t)s0 * IN_DIM + sub * 4);
        const float4 v1 = *reinterpret_cast<const float4*>(X + (size_t)s1 * IN_DIM + sub * 4);
        const float4 v2 = *reinterpret_cast<const float4*>(X + (size_t)s2 * IN_DIM + sub * 4);
        const float4 v3 = *reinterpret_cast<const float4*>(X + (size_t)s3 * IN_DIM + sub * 4);
        acc.x += v0.x + v1.x + v2.x + v3.x;
        acc.y += v0.y + v1.y + v2.y + v3.y;
        acc.z += v0.z + v1.z + v2.z + v3.z;
        acc.w += v0.w + v1.w + v2.w + v3.w;
    }
    for (; e < end; ++e) {
        const int s = src_sorted[e];
        const float4 v = *reinterpret_cast<const float4*>(X + (size_t)s * IN_DIM + sub * 4);
        acc.x += v.x; acc.y += v.y; acc.z += v.z; acc.w += v.w;
    }

    ushort4 hi, lo;
    hi.x = bf16_hi(acc.x); lo.x = bf16_hi(acc.x - bf16_tof(hi.x));
    hi.y = bf16_hi(acc.y); lo.y = bf16_hi(acc.y - bf16_tof(hi.y));
    hi.z = bf16_hi(acc.z); lo.z = bf16_hi(acc.z - bf16_tof(hi.z));
    hi.w = bf16_hi(acc.w); lo.w = bf16_hi(acc.w - bf16_tof(hi.w));
    *reinterpret_cast<ushort4*>(Ahi + (size_t)u * IN_DIM + sub * 4) = hi;
    *reinterpret_cast<ushort4*>(Alo + (size_t)u * IN_DIM + sub * 4) = lo;
}

// ===========================================================================
// xsplit: X f32 -> per-node packed [hi[128] | lo[128]] bf16, stored in d_out.
// ===========================================================================
__global__ void xsplit_kernel(const float* __restrict__ X,
                              unsigned short* __restrict__ Xsp, int n_nodes) {
    int i = blockIdx.x * blockDim.x + threadIdx.x;   // n_nodes*32 float4 groups
    if (i >= n_nodes * 32) return;
    const int node = i >> 5, g = i & 31;
    const float4 x = *reinterpret_cast<const float4*>(X + (size_t)node * IN_DIM + g * 4);
    ushort4 hi, lo;
    hi.x = bf16_hi(x.x); lo.x = bf16_hi(x.x - bf16_tof(hi.x));
    hi.y = bf16_hi(x.y); lo.y = bf16_hi(x.y - bf16_tof(hi.y));
    hi.z = bf16_hi(x.z); lo.z = bf16_hi(x.z - bf16_tof(hi.z));
    hi.w = bf16_hi(x.w); lo.w = bf16_hi(x.w - bf16_tof(hi.w));
    *reinterpret_cast<ushort4*>(Xsp + (size_t)node * 256 + g * 4) = hi;
    *reinterpret_cast<ushort4*>(Xsp + (size_t)node * 256 + 128 + g * 4) = lo;
}

__global__ void wsplit_kernel(const float* __restrict__ W1,
                              const float* __restrict__ W2,
                              unsigned short* __restrict__ W1h,
                              unsigned short* __restrict__ W1l,
                              unsigned short* __restrict__ W2h,
                              unsigned short* __restrict__ W2l) {
    int i = blockIdx.x * blockDim.x + threadIdx.x;   // 16384
    if (i >= OUT_DIM * IN_DIM) return;
    float a = W1[i], b = W2[i];
    unsigned short ah = bf16_hi(a), bh = bf16_hi(b);
    W1h[i] = ah; W1l[i] = bf16_hi(a - bf16_tof(ah));
    W2h[i] = bh; W2l[i] = bf16_hi(b - bf16_tof(bh));
}

// ===========================================================================
// MFMA GEMM: out[n][o] = relu( sum over 6 bf16 K-segments + bias )
// segs: Xhi*W1h, Xhi*W1l, Xlo*W1h, Ahi*W2h, Ahi*W2l, Alo*W2h  (K=6*128=768)
// ===========================================================================
__global__ __launch_bounds__(256, 4)
void mfma_gemm_kernel(const unsigned short* Xsp,          // aliases `out`!
                      const unsigned short* __restrict__ Ahi,
                      const unsigned short* __restrict__ Alo,
                      const unsigned short* __restrict__ W1h,
                      const unsigned short* __restrict__ W1l,
                      const unsigned short* __restrict__ W2h,
                      const unsigned short* __restrict__ W2l,
                      const float* __restrict__ bias,
                      float* out,
                      int n_nodes) {
    __shared__ unsigned short Fs[64 * 64];    // [node][k] swizzled, 8 KB
    __shared__ unsigned short Ws[128 * 64];   // [o][k]    swizzled, 16 KB

    const int tid  = threadIdx.x;
    const int lane = tid & 63;
    const int wid  = tid >> 6;
    const int wm   = wid >> 1;          // 0..1  (node half)
    const int wn   = wid & 1;           // 0..1  (out half)
    const int lr   = lane & 15;
    const int lk   = lane >> 4;         // 0..3
    const int node0 = blockIdx.x * 64;

    const int fr = tid >> 3;            // base row 0..31
    const int c  = tid & 7;             // chunk in row
    const int swz = (c ^ (fr & 7)) * 8; // LDS-side swizzled element offset

    float4v acc[2][4];
    #pragma unroll
    for (int mi = 0; mi < 2; ++mi)
        #pragma unroll
        for (int ni = 0; ni < 4; ++ni) acc[mi][ni] = (float4v)0.f;

    const unsigned short* wseg[6] = {W1h, W1l, W1h, W2h, W2l, W2h};

    short8v fv[2], wv[4];

    // ---- prologue: load tile 0 ----
    {
        const int khalf = 0;
        #pragma unroll
        for (int j = 0; j < 2; ++j) {
            const int node = node0 + fr + j * 32;
            short8v v = (short8v)0;
            if (node < n_nodes)
                v = *reinterpret_cast<const short8v*>(
                    Xsp + (size_t)node * 256 + khalf + c * 8);
            fv[j] = v;
        }
        #pragma unroll
        for (int j = 0; j < 4; ++j)
            wv[j] = *reinterpret_cast<const short8v*>(
                wseg[0] + (size_t)(fr + j * 32) * 128 + khalf + c * 8);
    }

    #pragma unroll
    for (int t = 0; t < 12; ++t) {
        __syncthreads();   // protect LDS from previous tile's readers
        #pragma unroll
        for (int j = 0; j < 2; ++j)
            *reinterpret_cast<short8v*>(&Fs[(fr + j * 32) * 64 + swz]) = fv[j];
        #pragma unroll
        for (int j = 0; j < 4; ++j)
            *reinterpret_cast<short8v*>(&Ws[(fr + j * 32) * 64 + swz]) = wv[j];
        __syncthreads();

        // ---- prefetch tile t+1 (hides under MFMA phase) ----
        if (t < 11) {
            const int tn = t + 1;
            const int seg = tn >> 1;
            const int khalf = (tn & 1) * 64;
            #pragma unroll
            for (int j = 0; j < 2; ++j) {
                const int node = node0 + fr + j * 32;
                short8v v = (short8v)0;
                if (node < n_nodes) {
                    if (seg < 3) {
                        v = *reinterpret_cast<const short8v*>(
                            Xsp + (size_t)node * 256 + (seg == 2 ? 128 : 0) +
                            khalf + c * 8);
                    } else {
                        const unsigned short* Ap = (seg == 5) ? Alo : Ahi;
                        v = *reinterpret_cast<const short8v*>(
                            Ap + (size_t)node * 128 + khalf + c * 8);
                    }
                }
                fv[j] = v;
            }
            #pragma unroll
            for (int j = 0; j < 4; ++j)
                wv[j] = *reinterpret_cast<const short8v*>(
                    wseg[seg] + (size_t)(fr + j * 32) * 128 + khalf + c * 8);
        }

        // ---- compute tile t ----
        #pragma unroll
        for (int ks = 0; ks < 2; ++ks) {
            const int cc = ((ks * 4 + lk) ^ (lr & 7)) * 8;
            short8v a[2], b[4];
            #pragma unroll
            for (int mi = 0; mi < 2; ++mi) {
                const int row = wm * 32 + mi * 16 + lr;
                a[mi] = *reinterpret_cast<const short8v*>(&Fs[row * 64 + cc]);
            }
            #pragma unroll
            for (int ni = 0; ni < 4; ++ni) {
                const int o = wn * 64 + ni * 16 + lr;
                b[ni] = *reinterpret_cast<const short8v*>(&Ws[o * 64 + cc]);
            }
            #pragma unroll
            for (int mi = 0; mi < 2; ++mi)
                #pragma unroll
                for (int ni = 0; ni < 4; ++ni)
                    acc[mi][ni] = __builtin_amdgcn_mfma_f32_16x16x32_bf16(
                        a[mi], b[ni], acc[mi][ni], 0, 0, 0);
        }
    }

    // ---- epilogue: bias + relu; C/D layout col=lane&15, row=(lane>>4)*4+r ----
    #pragma unroll
    for (int ni = 0; ni < 4; ++ni) {
        const int o = wn * 64 + ni * 16 + lr;
        const float bo = bias[o];
        #pragma unroll
        for (int mi = 0; mi < 2; ++mi) {
            const int nodeb = node0 + wm * 32 + mi * 16 + lk * 4;
            #pragma unroll
            for (int r = 0; r < 4; ++r) {
                const int node = nodeb + r;
                if (node < n_nodes)
                    out[(size_t)node * OUT_DIM + o] =
                        fmaxf(acc[mi][ni][r] + bo, 0.f);
            }
        }
    }
}

// ===========================================================================
// f32 fallback GEMM (R2-proven)
// ===========================================================================
__global__ __launch_bounds__(256)
void gemm_kernel(const float* __restrict__ X,
                 const float* __restrict__ A,
                 const float* __restrict__ Wself,
                 const float* __restrict__ Wneigh,
                 const float* __restrict__ bias,
                 float* __restrict__ out,
                 int n_nodes) {
    __shared__ alignas(16) float Wt[KT][132];
    __shared__ alignas(16) float Xs[BM][KT + 4];

    const int tid   = threadIdx.x;
    const int o_grp = tid & 31;
    const int n_grp = tid >> 5;
    const int node0 = blockIdx.x * BM;

    float acc[8][4];
    #pragma unroll
    for (int i = 0; i < 8; ++i)
        #pragma unroll
        for (int j = 0; j < 4; ++j) acc[i][j] = 0.f;

    for (int kt = 0; kt < 2 * IN_DIM; kt += KT) {
        const float* Wsrc = (kt < IN_DIM) ? Wself : Wneigh;
        const float* Fsrc = (kt < IN_DIM) ? X : A;
        const int kbase = kt & (IN_DIM - 1);
        __syncthreads();
        {
            const int k4 = tid & 7;
            int o = tid >> 3;
            #pragma unroll
            for (int p = 0; p < 4; ++p, o += 32) {
                float4 w = *reinterpret_cast<const float4*>(
                    Wsrc + o * IN_DIM + kbase + k4 * 4);
                Wt[k4 * 4 + 0][o] = w.x;
                Wt[k4 * 4 + 1][o] = w.y;
                Wt[k4 * 4 + 2][o] = w.z;
                Wt[k4 * 4 + 3][o] = w.w;
            }
        }
        {
            const int k4 = tid & 7;
            int n = tid >> 3;
            #pragma unroll
            for (int p = 0; p < 2; ++p, n += 32) {
                const int node = node0 + n;
                float4 x = make_float4(0.f, 0.f, 0.f, 0.f);
                if (node < n_nodes)
                    x = *reinterpret_cast<const float4*>(
                        Fsrc + (size_t)node * IN_DIM + kbase + k4 * 4);
                *reinterpret_cast<float4*>(&Xs[n][k4 * 4]) = x;
            }
        }
        __syncthreads();
        #pragma unroll
        for (int k4 = 0; k4 < KT; k4 += 4) {
            float4 w0 = *reinterpret_cast<const float4*>(&Wt[k4 + 0][o_grp * 4]);
            float4 w1 = *reinterpret_cast<const float4*>(&Wt[k4 + 1][o_grp * 4]);
            float4 w2 = *reinterpret_cast<const float4*>(&Wt[k4 + 2][o_grp * 4]);
            float4 w3 = *reinterpret_cast<const float4*>(&Wt[k4 + 3][o_grp * 4]);
            #pragma unroll
            for (int nn = 0; nn < 8; ++nn) {
                float4 x = *reinterpret_cast<const float4*>(
                    &Xs[n_grp * 8 + nn][k4]);
                acc[nn][0] = fmaf(x.x, w0.x, acc[nn][0]);
                acc[nn][0] = fmaf(x.y, w1.x, acc[nn][0]);
                acc[nn][0] = fmaf(x.z, w2.x, acc[nn][0]);
                acc[nn][0] = fmaf(x.w, w3.x, acc[nn][0]);
                acc[nn][1] = fmaf(x.x, w0.y, acc[nn][1]);
                acc[nn][1] = fmaf(x.y, w1.y, acc[nn][1]);
                acc[nn][1] = fmaf(x.z, w2.y, acc[nn][1]);
                acc[nn][1] = fmaf(x.w, w3.y, acc[nn][1]);
                acc[nn][2] = fmaf(x.x, w0.z, acc[nn][2]);
                acc[nn][2] = fmaf(x.y, w1.z, acc[nn][2]);
                acc[nn][2] = fmaf(x.z, w2.z, acc[nn][2]);
                acc[nn][2] = fmaf(x.w, w3.z, acc[nn][2]);
                acc[nn][3] = fmaf(x.x, w0.w, acc[nn][3]);
                acc[nn][3] = fmaf(x.y, w1.w, acc[nn][3]);
                acc[nn][3] = fmaf(x.z, w2.w, acc[nn][3]);
                acc[nn][3] = fmaf(x.w, w3.w, acc[nn][3]);
            }
        }
    }

    const float4 b = *reinterpret_cast<const float4*>(bias + o_grp * 4);
    #pragma unroll
    for (int nn = 0; nn < 8; ++nn) {
        const int node = node0 + n_grp * 8 + nn;
        if (node < n_nodes) {
            float4 r;
            r.x = fmaxf(acc[nn][0] + b.x, 0.f);
            r.y = fmaxf(acc[nn][1] + b.y, 0.f);
            r.z = fmaxf(acc[nn][2] + b.z, 0.f);
            r.w = fmaxf(acc[nn][3] + b.w, 0.f);
            *reinterpret_cast<float4*>(
                out + (size_t)node * OUT_DIM + o_grp * 4) = r;
        }
    }
}

// ===========================================================================
extern "C" void kernel_launch(void* const* d_in, const int* in_sizes, int n_in,
                              void* d_out, int out_size, void* d_ws, size_t ws_size,
                              hipStream_t stream) {
    const float* X      = (const float*)d_in[0];
    const int*   src    = (const int*)d_in[1];
    const int*   dst    = (const int*)d_in[2];
    const float* Wself  = (const float*)d_in[3];
    const float* Wneigh = (const float*)d_in[4];
    const float* bias   = (const float*)d_in[5];
    float*       out    = (float*)d_out;

    const int n_nodes = in_sizes[0] / IN_DIM;
    const int n_edges = in_sizes[1];
    const int nb = (n_nodes + 255) / 256;

    char* w = (char*)d_ws;
    auto take = [&](size_t bytes) {
        char* p = w;
        w += (bytes + 15) & ~(size_t)15;
        return p;
    };
    unsigned short* Ahi = (unsigned short*)take((size_t)n_nodes * IN_DIM * 2);
    unsigned short* Alo = (unsigned short*)take((size_t)n_nodes * IN_DIM * 2);
    int* counts    = (int*)take((size_t)n_nodes * sizeof(int));
    int* offs      = (int*)take((size_t)n_nodes * sizeof(int));
    int* cursor    = (int*)take((size_t)n_nodes * sizeof(int));
    int* bsums     = (int*)take((size_t)nb * sizeof(int));
    int* srcsorted = (int*)take((size_t)n_edges * sizeof(int));
    unsigned short* W1h = (unsigned short*)take((size_t)OUT_DIM * IN_DIM * 2);
    unsigned short* W1l = (unsigned short*)take((size_t)OUT_DIM * IN_DIM * 2);
    unsigned short* W2h = (unsigned short*)take((size_t)OUT_DIM * IN_DIM * 2);
    unsigned short* W2l = (unsigned short*)take((size_t)OUT_DIM * IN_DIM * 2);
    const size_t needed = (size_t)(w - (char*)d_ws);

    if (needed <= ws_size) {
        // ---- CSR binning + bf16x2-split MFMA path ----
        hipMemsetAsync(counts, 0, (size_t)n_nodes * sizeof(int), stream);
        hist_kernel<<<(n_edges / 4 + 256) / 256 + 1, 256, 0, stream>>>(dst, counts, n_edges);
        scan1_kernel<<<nb, 256, 0, stream>>>(counts, offs, bsums, n_nodes);
        scan2_kernel<<<1, 256, 0, stream>>>(bsums, nb);
        scan3_kernel<<<nb, 256, 0, stream>>>(offs, bsums, cursor, n_nodes);
        const int chunk = (n_nodes + NPART - 1) / NPART;
        bucket_part_kernel<<<2048, 256, 0, stream>>>(src, dst, cursor,
                                                     srcsorted, n_edges, chunk);
        unsigned short* Xsp = (unsigned short*)d_out;   // X hi/lo packed in out slots
        xsplit_kernel<<<(n_nodes * 32 + 255) / 256, 256, 0, stream>>>(X, Xsp, n_nodes);
        wsplit_kernel<<<(OUT_DIM * IN_DIM + 255) / 256, 256, 0, stream>>>(
            Wself, Wneigh, W1h, W1l, W2h, W2l);
        accum_split_kernel<<<(n_nodes + 7) / 8, 256, 0, stream>>>(
            X, offs, srcsorted, Ahi, Alo, n_nodes, n_edges);
        mfma_gemm_kernel<<<(n_nodes + 63) / 64, 256, 0, stream>>>(
            Xsp, Ahi, Alo, W1h, W1l, W2h, W2l, bias, out, n_nodes);
    } else {
        // ---- fallback: f32 atomic scatter + f32 vector GEMM ----
        float* A = (float*)d_ws;
        hipMemsetAsync(A, 0, (size_t)n_nodes * IN_DIM * sizeof(float), stream);
        const long long sthreads = (long long)n_edges * 32;
        const int sblocks = (int)((sthreads + 255) / 256);
        scatter_kernel<<<sblocks, 256, 0, stream>>>(X, src, dst, A, n_edges);
        gemm_kernel<<<(n_nodes + BM - 1) / BM, 256, 0, stream>>>(
            X, A, Wself, Wneigh, bias, out, n_nodes);
    }
}